// Round 8
// baseline (129.987 us; speedup 1.0000x reference)
//
#include <hip/hip_runtime.h>
#include <math.h>

#define VOCAB  30522
#define HIDDEN 768
#define EMB    128
#define BATCH  1024
#define QLEN   32
#define DLEN   180
#define NEGV   (-1e4f)

typedef __attribute__((ext_vector_type(8))) short bf16x8;
typedef __attribute__((ext_vector_type(4))) float f32x4;

__device__ __forceinline__ unsigned short f2bf(float x) {
  union { float f; unsigned u; } v; v.f = x;
  unsigned r = v.u + 0x7FFFu + ((v.u >> 16) & 1u);
  return (unsigned short)(r >> 16);
}
__device__ __forceinline__ float bf2f(unsigned short h) {
  union { float f; unsigned u; } v; v.u = ((unsigned)h) << 16;
  return v.f;
}
// split 2 fp32 -> packed bf16 hi pair + packed bf16 lo pair
__device__ __forceinline__ void split_pk(float x0, float x1, unsigned& h, unsigned& l) {
  asm("v_cvt_pk_bf16_f32 %0, %1, %2" : "=v"(h) : "v"(x0), "v"(x1));
  float h0, h1;
  h0 = __uint_as_float(h << 16);
  h1 = __uint_as_float(h & 0xffff0000u);
  float l0 = x0 - h0, l1 = x1 - h1;
  asm("v_cvt_pk_bf16_f32 %0, %1, %2" : "=v"(l) : "v"(l0), "v"(l1));
}

// ---------------------------------------------------------------------------
// Kernel 0: W [768][128] fp32 -> fragment-major bf16 hi/lo tables.
// wf[(kkg*8 + nt)*64 + lane][j] holds W[kkg*32 + (lane>>4)*8 + j][nt*16 + (lane&15)]
// ---------------------------------------------------------------------------
__global__ __launch_bounds__(256) void prep_wfrag(
    const float* __restrict__ W, unsigned short* __restrict__ wfh,
    unsigned short* __restrict__ wfl) {
  int g = blockIdx.x * 256 + threadIdx.x;   // 0..12287
  if (g >= 24 * 8 * 64) return;
  int lane = g & 63, nt = (g >> 6) & 7, kk = g >> 9;
  int lr = lane & 15, kq = lane >> 4;
  int n = nt * 16 + lr;
  int k0 = kk * 32 + kq * 8;
  unsigned short hh[8], ll[8];
#pragma unroll
  for (int j = 0; j < 8; ++j) {
    float x = W[(size_t)(k0 + j) * EMB + n];
    unsigned short hi = f2bf(x);
    hh[j] = hi;
    ll[j] = f2bf(x - bf2f(hi));
  }
  size_t base = (size_t)g * 8;
#pragma unroll
  for (int j = 0; j < 2; ++j) {
    *(ushort4*)(wfh + base + j * 4) = *(ushort4*)(hh + j * 4);
    *(ushort4*)(wfl + base + j * 4) = *(ushort4*)(ll + j * 4);
  }
}

// ---------------------------------------------------------------------------
// Kernel 1: pebf[v] = bf16(normalize(emb[v] @ W + b)), bf16x3-split MFMA.
// 954 blocks x 128 thr (2 waves x 16 rows). Wave tile 16x128, acc[8].
// A: HBM -> registers directly (per-lane contiguous 32B = the A-frag).
// B: fragment table staged through LDS (16KB/chunk, dbuf), shared by waves.
// Pipeline: at chunk T, ds_write B(T+1) (regs loaded a full chunk ago ->
// its vmcnt wait is free), issue loads for T+2, MFMA on LDS(T), syncthreads.
// The barrier's vmcnt(0) drain only covers loads issued a full chunk earlier
// -> ~zero stall, ~24KB/block in flight against HBM latency.
// ---------------------------------------------------------------------------
__global__ __launch_bounds__(128) void colbert_proj_mfma(
    const float* __restrict__ emb, const unsigned short* __restrict__ wfh,
    const unsigned short* __restrict__ wfl, const float* __restrict__ bias,
    unsigned short* __restrict__ pebf) {
  __shared__ __align__(16) char smem[32768];  // 2 x (Bh 8K + Bl 8K)

  const int tid  = threadIdx.x;
  const int lane = tid & 63;
  const int wm   = tid >> 6;     // wave row-half: rows wm*16..+15
  const int lr   = lane & 15;
  const int kq   = lane >> 4;
  const int row0 = blockIdx.x * 32;

  int grow = row0 + wm * 16 + lr;
  if (grow > VOCAB - 1) grow = VOCAB - 1;
  const float* aptr = emb + (size_t)grow * HIDDEN + kq * 8;

  f32x4 acc[8];
#pragma unroll
  for (int nt = 0; nt < 8; ++nt) acc[nt] = (f32x4)0.f;

  float4 arA[2][2];   // [parity][half]: this lane's A-frag source (8 fp32)
  uint4  breg[8];     // staged B: 4 hi + 4 lo (one 32-k chunk)

#define BLOAD(T)                                                               \
  {                                                                            \
    _Pragma("unroll")                                                          \
    for (int i = 0; i < 4; ++i) {                                              \
      size_t s = (size_t)(T) * 4096 + (size_t)(i * 128 + tid) * 8;             \
      breg[i]     = *(const uint4*)(wfh + s);                                  \
      breg[4 + i] = *(const uint4*)(wfl + s);                                  \
    }                                                                          \
  }

#define BWRITE(BUF)                                                            \
  {                                                                            \
    char* d = smem + (BUF) * 16384;                                            \
    _Pragma("unroll")                                                          \
    for (int i = 0; i < 4; ++i) {                                              \
      *(uint4*)(d + (i * 128 + tid) * 16)        = breg[i];                    \
      *(uint4*)(d + 8192 + (i * 128 + tid) * 16) = breg[4 + i];                \
    }                                                                          \
  }

  // prologue: B(0)->LDS0, breg=B(1), arA = A(0),A(1); one full drain.
  BLOAD(0);
  arA[0][0] = *(const float4*)(aptr);
  arA[0][1] = *(const float4*)(aptr + 4);
  arA[1][0] = *(const float4*)(aptr + 32);
  arA[1][1] = *(const float4*)(aptr + 36);
  BWRITE(0);
  BLOAD(1);
  __syncthreads();

  // chunk T (parity P): LDS buf P holds B(T); breg holds B(T+1); arA[P]=A(T).
#define CHUNK(T, P)                                                            \
  {                                                                            \
    union { unsigned u[4]; bf16x8 v; } Ah_, Al_;                               \
    split_pk(arA[P][0].x, arA[P][0].y, Ah_.u[0], Al_.u[0]);                    \
    split_pk(arA[P][0].z, arA[P][0].w, Ah_.u[1], Al_.u[1]);                    \
    split_pk(arA[P][1].x, arA[P][1].y, Ah_.u[2], Al_.u[2]);                    \
    split_pk(arA[P][1].z, arA[P][1].w, Ah_.u[3], Al_.u[3]);                    \
    if ((T) + 1 < 24) BWRITE((P) ^ 1);      /* B(T+1): regs 1 chunk old */     \
    if ((T) + 2 < 24) {                                                        \
      BLOAD((T) + 2);                       /* issue now, land by T+1 end */   \
      arA[P][0] = *(const float4*)(aptr + ((T) + 2) * 32);                     \
      arA[P][1] = *(const float4*)(aptr + ((T) + 2) * 32 + 4);                 \
    }                                                                          \
    char* rb = smem + (P) * 16384;                                             \
    _Pragma("unroll")                                                          \
    for (int nt = 0; nt < 8; ++nt) {                                           \
      bf16x8 bh = *(bf16x8*)(rb + nt * 1024 + lane * 16);                      \
      bf16x8 bl = *(bf16x8*)(rb + 8192 + nt * 1024 + lane * 16);               \
      acc[nt] = __builtin_amdgcn_mfma_f32_16x16x32_bf16(Ah_.v, bh, acc[nt], 0, 0, 0); \
      acc[nt] = __builtin_amdgcn_mfma_f32_16x16x32_bf16(Ah_.v, bl, acc[nt], 0, 0, 0); \
      acc[nt] = __builtin_amdgcn_mfma_f32_16x16x32_bf16(Al_.v, bh, acc[nt], 0, 0, 0); \
    }                                                                          \
    __syncthreads();                                                           \
  }

  for (int tt = 0; tt < 24; tt += 2) {
    CHUNK(tt, 0);
    CHUNK(tt + 1, 1);
  }

  // epilogue: bias + L2-normalize -> bf16. Reuse LDS as fp32 ep[32][132].
  float* ep = (float*)smem;
#pragma unroll
  for (int nt = 0; nt < 8; ++nt) {
    float bb = bias[nt * 16 + lr];
#pragma unroll
    for (int j = 0; j < 4; ++j) {
      int r = wm * 16 + kq * 4 + j;   // C: col=lane&15, row=(lane>>4)*4+j
      ep[r * 132 + nt * 16 + lr] = acc[nt][j] + bb;
    }
  }
  __syncthreads();
  {
    int row = tid >> 2, quad = tid & 3;   // 4 threads/row, 32 cols each
    float4 vv[8];
    float ss = 0.f;
#pragma unroll
    for (int i = 0; i < 8; ++i) {
      vv[i] = *(float4*)&ep[row * 132 + quad * 32 + i * 4];
      ss += vv[i].x * vv[i].x + vv[i].y * vv[i].y + vv[i].z * vv[i].z + vv[i].w * vv[i].w;
    }
    ss += __shfl_xor(ss, 1);
    ss += __shfl_xor(ss, 2);
    float sc = 1.f / (sqrtf(ss) + 1e-12f);
    int gr = row0 + row;
    if (gr < VOCAB) {
      unsigned pk[16];              // FIX: full 32 cols (R6/R7 wrote only 16)
#pragma unroll
      for (int i = 0; i < 8; ++i) {
        pk[i * 2 + 0] = (unsigned)f2bf(vv[i].x * sc) | ((unsigned)f2bf(vv[i].y * sc) << 16);
        pk[i * 2 + 1] = (unsigned)f2bf(vv[i].z * sc) | ((unsigned)f2bf(vv[i].w * sc) << 16);
      }
      uint4* dst = (uint4*)(pebf + (size_t)gr * EMB + quad * 32);
      dst[0] = make_uint4(pk[0],  pk[1],  pk[2],  pk[3]);
      dst[1] = make_uint4(pk[4],  pk[5],  pk[6],  pk[7]);
      dst[2] = make_uint4(pk[8],  pk[9],  pk[10], pk[11]);
      dst[3] = make_uint4(pk[12], pk[13], pk[14], pk[15]);
    }
  }
#undef BLOAD
#undef BWRITE
#undef CHUNK
}

// ---------------------------------------------------------------------------
// Kernel 2: per-batch MaxSim via MFMA, fragments gathered straight from the
// L2/L3-resident bf16 table (no data staging). One block = one batch.
// ---------------------------------------------------------------------------
__global__ __launch_bounds__(256) void colbert_score_mfma(
    const int* __restrict__ qids, const int* __restrict__ qmask,
    const int* __restrict__ dids, const int* __restrict__ dmask,
    const unsigned short* __restrict__ pebf, float* __restrict__ out) {
  __shared__ int sqid[32];
  __shared__ int sdid[192];
  __shared__ unsigned char smsk[192];
  __shared__ float wmax[4][32];

  const int b    = blockIdx.x;
  const int tid  = threadIdx.x;
  const int lane = tid & 63;
  const int wid  = tid >> 6;
  const int lr   = lane & 15;
  const int kq   = lane >> 4;

  if (tid < 32) sqid[tid] = qids[b * QLEN + tid];
  if (tid < 192) {
    if (tid < DLEN) {
      sdid[tid] = dids[b * DLEN + tid];
      smsk[tid] = (unsigned char)(dmask[b * DLEN + tid] > 0 ? 1 : 0);
    } else {
      sdid[tid] = 0;
      smsk[tid] = 0;
    }
  }
  __syncthreads();

  bf16x8 af[2][4];
#pragma unroll
  for (int mi = 0; mi < 2; ++mi) {
    size_t base = (size_t)sqid[mi * 16 + lr] * EMB + kq * 8;
#pragma unroll
    for (int ks = 0; ks < 4; ++ks)
      af[mi][ks] = *(const bf16x8*)(pebf + base + ks * 32);
  }
  const int n0 = wid * 48;
  bf16x8 bfr[3][4];
#pragma unroll
  for (int ni = 0; ni < 3; ++ni) {
    size_t base = (size_t)sdid[n0 + ni * 16 + lr] * EMB + kq * 8;
#pragma unroll
    for (int ks = 0; ks < 4; ++ks)
      bfr[ni][ks] = *(const bf16x8*)(pebf + base + ks * 32);
  }

  f32x4 acc[2][3];
#pragma unroll
  for (int mi = 0; mi < 2; ++mi)
#pragma unroll
    for (int ni = 0; ni < 3; ++ni) acc[mi][ni] = (f32x4)0.f;

#pragma unroll
  for (int ks = 0; ks < 4; ++ks)
#pragma unroll
    for (int mi = 0; mi < 2; ++mi)
#pragma unroll
      for (int ni = 0; ni < 3; ++ni)
        acc[mi][ni] = __builtin_amdgcn_mfma_f32_16x16x32_bf16(af[mi][ks], bfr[ni][ks], acc[mi][ni], 0, 0, 0);

#pragma unroll
  for (int mi = 0; mi < 2; ++mi) {
#pragma unroll
    for (int j = 0; j < 4; ++j) {
      float m = -3.0e38f;
#pragma unroll
      for (int ni = 0; ni < 3; ++ni) {
        int t = n0 + ni * 16 + lr;
        float s = smsk[t] ? acc[mi][ni][j] : NEGV;
        m = fmaxf(m, s);
      }
#pragma unroll
      for (int x = 1; x < 16; x <<= 1) m = fmaxf(m, __shfl_xor(m, x));
      if (lr == 0) wmax[wid][mi * 16 + kq * 4 + j] = m;
    }
  }
  __syncthreads();

  if (tid < 32) {
    float m = fmaxf(fmaxf(wmax[0][tid], wmax[1][tid]),
                    fmaxf(wmax[2][tid], wmax[3][tid]));
    float s = m * (float)qmask[b * QLEN + tid];
#pragma unroll
    for (int x = 1; x < 32; x <<= 1) s += __shfl_xor(s, x);
    if (tid == 0) out[b] = s;
  }
}

// ---------------------------------------------------------------------------
extern "C" void kernel_launch(void* const* d_in, const int* in_sizes, int n_in,
                              void* d_out, int out_size, void* d_ws, size_t ws_size,
                              hipStream_t stream) {
  const int*   qids  = (const int*)d_in[0];
  const int*   qmask = (const int*)d_in[1];
  const int*   dids  = (const int*)d_in[2];
  const int*   dmask = (const int*)d_in[3];
  const float* emb   = (const float*)d_in[4];
  const float* W     = (const float*)d_in[5];
  const float* bias  = (const float*)d_in[6];
  float*       out   = (float*)d_out;

  char* ws = (char*)d_ws;
  unsigned short* pebf = (unsigned short*)ws;                 // 7,813,632 B
  unsigned short* wfh  = (unsigned short*)(ws + 7813632);     //   196,608 B
  unsigned short* wfl  = (unsigned short*)(ws + 7813632 + 196608);

  prep_wfrag<<<48, 256, 0, stream>>>(W, wfh, wfl);
  colbert_proj_mfma<<<(VOCAB + 31) / 32, 128, 0, stream>>>(emb, wfh, wfl, bias, pebf);
  colbert_score_mfma<<<BATCH, 256, 0, stream>>>(qids, qmask, dids, dmask, pebf, out);
}

// Round 9
// 51.942 us; speedup vs baseline: 2.5025x; 2.5025x over previous
//
#include <hip/hip_runtime.h>
#include <math.h>

#define VOCAB  30522
#define HIDDEN 768
#define EMB    128
#define BATCH  1024
#define QLEN   32
#define DLEN   180
#define NEGV   (-1e4f)

typedef __attribute__((ext_vector_type(8))) short bf16x8;
typedef __attribute__((ext_vector_type(4))) float f32x4;
typedef unsigned int u32;

__device__ __forceinline__ unsigned short f2bf(float x) {
  union { float f; unsigned u; } v; v.f = x;
  unsigned r = v.u + 0x7FFFu + ((v.u >> 16) & 1u);
  return (unsigned short)(r >> 16);
}
__device__ __forceinline__ float bf2f(unsigned short h) {
  union { float f; unsigned u; } v; v.u = ((unsigned)h) << 16;
  return v.f;
}
// split 2 fp32 -> packed bf16 hi pair + packed bf16 lo pair
__device__ __forceinline__ void split_pk(float x0, float x1, unsigned& h, unsigned& l) {
  asm("v_cvt_pk_bf16_f32 %0, %1, %2" : "=v"(h) : "v"(x0), "v"(x1));
  float h0, h1;
  h0 = __uint_as_float(h << 16);
  h1 = __uint_as_float(h & 0xffff0000u);
  float l0 = x0 - h0, l1 = x1 - h1;
  asm("v_cvt_pk_bf16_f32 %0, %1, %2" : "=v"(l) : "v"(l0), "v"(l1));
}
// async 16B global -> LDS (direct, no VGPR roundtrip)
__device__ __forceinline__ void gload16(const float* g, void* l) {
  __builtin_amdgcn_global_load_lds(
      (const __attribute__((address_space(1))) u32*)g,
      (__attribute__((address_space(3))) u32*)l, 16, 0, 0);
}

// ---------------------------------------------------------------------------
// Kernel 0: W [768][128] fp32 -> fragment-major bf16 hi/lo tables.
// wf[(c32*8 + nt)*64 + lane][j] holds W[c32*32 + (lane>>4)*8 + j][nt*16 + (lane&15)]
// ---------------------------------------------------------------------------
__global__ __launch_bounds__(256) void prep_wfrag(
    const float* __restrict__ W, unsigned short* __restrict__ wfh,
    unsigned short* __restrict__ wfl) {
  int g = blockIdx.x * 256 + threadIdx.x;   // 0..12287
  if (g >= 24 * 8 * 64) return;
  int lane = g & 63, nt = (g >> 6) & 7, kk = g >> 9;
  int lr = lane & 15, kq = lane >> 4;
  int n = nt * 16 + lr;
  int k0 = kk * 32 + kq * 8;
  unsigned short hh[8], ll[8];
#pragma unroll
  for (int j = 0; j < 8; ++j) {
    float x = W[(size_t)(k0 + j) * EMB + n];
    unsigned short hi = f2bf(x);
    hh[j] = hi;
    ll[j] = f2bf(x - bf2f(hi));
  }
  size_t base = (size_t)g * 8;
#pragma unroll
  for (int j = 0; j < 2; ++j) {
    *(ushort4*)(wfh + base + j * 4) = *(ushort4*)(hh + j * 4);
    *(ushort4*)(wfl + base + j * 4) = *(ushort4*)(ll + j * 4);
  }
}

// ---------------------------------------------------------------------------
// Kernel 1: pebf[v] = bf16(normalize(emb[v] @ W + b)), bf16x3-split MFMA.
// 954 blocks x 256 thr (4 waves, each an n-strip of 32 cols; wave tile 32x32).
// K in 12 chunks of BK=64.
// A: raw fp32 HBM -> LDS via global_load_lds (linear dest, pre-swizzled
//    source, XOR-swizzled read), split to bf16 hi/lo ON READ (VALU is idle).
// B: L2-resident fragment table -> 16 VGPRs per chunk. Minimal live state
//    (~80 VGPR) — R8's 155MB spill traffic is the thing being eliminated.
// ---------------------------------------------------------------------------
__global__ __launch_bounds__(256) void colbert_proj_mfma(
    const float* __restrict__ emb, const unsigned short* __restrict__ wfh,
    const unsigned short* __restrict__ wfl, const float* __restrict__ bias,
    unsigned short* __restrict__ pebf) {
  __shared__ __align__(16) char smem[17408];  // dbuf 2x8KB; epilogue 16.9KB

  const int tid  = threadIdx.x;
  const int lane = tid & 63;
  const int wid  = tid >> 6;   // wave = n-strip (cols wid*32..+31)
  const int lr   = lane & 15;
  const int kq   = lane >> 4;
  const int row0 = blockIdx.x * 32;

  // gload source mapping for this thread's two 16B slots (p = tid, tid+256):
  // phys slot p -> row = p>>4, logical 16B-col = (p&15) ^ (row&7)
#define GSRC(P, HC)                                                            \
  (emb + (size_t)(row0 + ((P) >> 4) > VOCAB - 1 ? VOCAB - 1                    \
                                                : row0 + ((P) >> 4)) * HIDDEN  \
       + (HC) * 64 + (((P) & 15) ^ (((P) >> 4) & 7)) * 4)

#define GLOAD(HC, BUF)                                                         \
  {                                                                            \
    char* d = smem + (BUF) * 8192;                                             \
    gload16(GSRC(tid, HC),       d + tid * 16);                                \
    gload16(GSRC(tid + 256, HC), d + 4096 + tid * 16);                         \
  }

  f32x4 acc[2][2];
#pragma unroll
  for (int mi = 0; mi < 2; ++mi)
#pragma unroll
    for (int ni = 0; ni < 2; ++ni) acc[mi][ni] = (f32x4)0.f;

  GLOAD(0, 0);
  __syncthreads();   // drain prologue loads

  for (int hc = 0; hc < 12; ++hc) {
    const int cur = hc & 1;
    if (hc < 11) GLOAD(hc + 1, cur ^ 1);   // async into other buffer
    // B fragments for this chunk (L2-resident): 16 VGPRs
    bf16x8 bh[2][2], bl[2][2];
#pragma unroll
    for (int kk = 0; kk < 2; ++kk)
#pragma unroll
      for (int ni = 0; ni < 2; ++ni) {
        size_t g = ((size_t)((hc * 2 + kk) * 8 + wid * 2 + ni) * 64 + lane) * 8;
        bh[kk][ni] = *(const bf16x8*)(wfh + g);
        bl[kk][ni] = *(const bf16x8*)(wfl + g);
      }
    char* Ab = smem + cur * 8192;
#pragma unroll
    for (int kk = 0; kk < 2; ++kk) {
      // A fragments: read raw fp32 from swizzled LDS, split in-register
      bf16x8 ah[2], al[2];
#pragma unroll
      for (int mi = 0; mi < 2; ++mi) {
        int row = mi * 16 + lr;
        int base = row * 256 + kk * 128 + kq * 32;
        float4 x0 = *(float4*)(Ab + ((base)      ^ ((row & 7) << 4)));
        float4 x1 = *(float4*)(Ab + ((base + 16) ^ ((row & 7) << 4)));
        union { unsigned u[4]; bf16x8 v; } H, L;
        split_pk(x0.x, x0.y, H.u[0], L.u[0]);
        split_pk(x0.z, x0.w, H.u[1], L.u[1]);
        split_pk(x1.x, x1.y, H.u[2], L.u[2]);
        split_pk(x1.z, x1.w, H.u[3], L.u[3]);
        ah[mi] = H.v; al[mi] = L.v;
      }
#pragma unroll
      for (int mi = 0; mi < 2; ++mi)
#pragma unroll
        for (int ni = 0; ni < 2; ++ni) {
          acc[mi][ni] = __builtin_amdgcn_mfma_f32_16x16x32_bf16(ah[mi], bh[kk][ni], acc[mi][ni], 0, 0, 0);
          acc[mi][ni] = __builtin_amdgcn_mfma_f32_16x16x32_bf16(ah[mi], bl[kk][ni], acc[mi][ni], 0, 0, 0);
          acc[mi][ni] = __builtin_amdgcn_mfma_f32_16x16x32_bf16(al[mi], bh[kk][ni], acc[mi][ni], 0, 0, 0);
        }
    }
    __syncthreads();   // one barrier per chunk (drains next-chunk gloads too)
  }

  // epilogue: bias + L2-normalize -> bf16. Reuse LDS as fp32 ep[32][132].
  float* ep = (float*)smem;
#pragma unroll
  for (int ni = 0; ni < 2; ++ni) {
    int col = wid * 32 + ni * 16 + lr;
    float bb = bias[col];
#pragma unroll
    for (int mi = 0; mi < 2; ++mi)
#pragma unroll
      for (int j = 0; j < 4; ++j) {
        int r = mi * 16 + kq * 4 + j;   // C: col=lane&15, row=(lane>>4)*4+j
        ep[r * 132 + col] = acc[mi][ni][j] + bb;
      }
  }
  __syncthreads();
  {
    int row = tid >> 3, oct = tid & 7;   // 8 threads/row, 16 cols each
    float4 vv[4];
    float ss = 0.f;
#pragma unroll
    for (int i = 0; i < 4; ++i) {
      vv[i] = *(float4*)&ep[row * 132 + oct * 16 + i * 4];
      ss += vv[i].x * vv[i].x + vv[i].y * vv[i].y + vv[i].z * vv[i].z + vv[i].w * vv[i].w;
    }
    ss += __shfl_xor(ss, 1);
    ss += __shfl_xor(ss, 2);
    ss += __shfl_xor(ss, 4);
    float sc = 1.f / (sqrtf(ss) + 1e-12f);
    int gr = row0 + row;
    if (gr < VOCAB) {
      unsigned pk[8];
#pragma unroll
      for (int i = 0; i < 4; ++i) {
        pk[i * 2 + 0] = (unsigned)f2bf(vv[i].x * sc) | ((unsigned)f2bf(vv[i].y * sc) << 16);
        pk[i * 2 + 1] = (unsigned)f2bf(vv[i].z * sc) | ((unsigned)f2bf(vv[i].w * sc) << 16);
      }
      uint4* dst = (uint4*)(pebf + (size_t)gr * EMB + oct * 16);
      dst[0] = make_uint4(pk[0], pk[1], pk[2], pk[3]);
      dst[1] = make_uint4(pk[4], pk[5], pk[6], pk[7]);
    }
  }
#undef GSRC
#undef GLOAD
}

// ---------------------------------------------------------------------------
// Kernel 2: per-batch MaxSim via MFMA, fragments gathered straight from the
// L2/L3-resident bf16 table (no data staging). One block = one batch.
// ---------------------------------------------------------------------------
__global__ __launch_bounds__(256) void colbert_score_mfma(
    const int* __restrict__ qids, const int* __restrict__ qmask,
    const int* __restrict__ dids, const int* __restrict__ dmask,
    const unsigned short* __restrict__ pebf, float* __restrict__ out) {
  __shared__ int sqid[32];
  __shared__ int sdid[192];
  __shared__ unsigned char smsk[192];
  __shared__ float wmax[4][32];

  const int b    = blockIdx.x;
  const int tid  = threadIdx.x;
  const int lane = tid & 63;
  const int wid  = tid >> 6;
  const int lr   = lane & 15;
  const int kq   = lane >> 4;

  if (tid < 32) sqid[tid] = qids[b * QLEN + tid];
  if (tid < 192) {
    if (tid < DLEN) {
      sdid[tid] = dids[b * DLEN + tid];
      smsk[tid] = (unsigned char)(dmask[b * DLEN + tid] > 0 ? 1 : 0);
    } else {
      sdid[tid] = 0;
      smsk[tid] = 0;
    }
  }
  __syncthreads();

  bf16x8 af[2][4];
#pragma unroll
  for (int mi = 0; mi < 2; ++mi) {
    size_t base = (size_t)sqid[mi * 16 + lr] * EMB + kq * 8;
#pragma unroll
    for (int ks = 0; ks < 4; ++ks)
      af[mi][ks] = *(const bf16x8*)(pebf + base + ks * 32);
  }
  const int n0 = wid * 48;
  bf16x8 bfr[3][4];
#pragma unroll
  for (int ni = 0; ni < 3; ++ni) {
    size_t base = (size_t)sdid[n0 + ni * 16 + lr] * EMB + kq * 8;
#pragma unroll
    for (int ks = 0; ks < 4; ++ks)
      bfr[ni][ks] = *(const bf16x8*)(pebf + base + ks * 32);
  }

  f32x4 acc[2][3];
#pragma unroll
  for (int mi = 0; mi < 2; ++mi)
#pragma unroll
    for (int ni = 0; ni < 3; ++ni) acc[mi][ni] = (f32x4)0.f;

#pragma unroll
  for (int ks = 0; ks < 4; ++ks)
#pragma unroll
    for (int mi = 0; mi < 2; ++mi)
#pragma unroll
      for (int ni = 0; ni < 3; ++ni)
        acc[mi][ni] = __builtin_amdgcn_mfma_f32_16x16x32_bf16(af[mi][ks], bfr[ni][ks], acc[mi][ni], 0, 0, 0);

#pragma unroll
  for (int mi = 0; mi < 2; ++mi) {
#pragma unroll
    for (int j = 0; j < 4; ++j) {
      float m = -3.0e38f;
#pragma unroll
      for (int ni = 0; ni < 3; ++ni) {
        int t = n0 + ni * 16 + lr;
        float s = smsk[t] ? acc[mi][ni][j] : NEGV;
        m = fmaxf(m, s);
      }
#pragma unroll
      for (int x = 1; x < 16; x <<= 1) m = fmaxf(m, __shfl_xor(m, x));
      if (lr == 0) wmax[wid][mi * 16 + kq * 4 + j] = m;
    }
  }
  __syncthreads();

  if (tid < 32) {
    float m = fmaxf(fmaxf(wmax[0][tid], wmax[1][tid]),
                    fmaxf(wmax[2][tid], wmax[3][tid]));
    float s = m * (float)qmask[b * QLEN + tid];
#pragma unroll
    for (int x = 1; x < 32; x <<= 1) s += __shfl_xor(s, x);
    if (tid == 0) out[b] = s;
  }
}

// ---------------------------------------------------------------------------
extern "C" void kernel_launch(void* const* d_in, const int* in_sizes, int n_in,
                              void* d_out, int out_size, void* d_ws, size_t ws_size,
                              hipStream_t stream) {
  const int*   qids  = (const int*)d_in[0];
  const int*   qmask = (const int*)d_in[1];
  const int*   dids  = (const int*)d_in[2];
  const int*   dmask = (const int*)d_in[3];
  const float* emb   = (const float*)d_in[4];
  const float* W     = (const float*)d_in[5];
  const float* bias  = (const float*)d_in[6];
  float*       out   = (float*)d_out;

  char* ws = (char*)d_ws;
  unsigned short* pebf = (unsigned short*)ws;                 // 7,813,632 B
  unsigned short* wfh  = (unsigned short*)(ws + 7813632);     //   196,608 B
  unsigned short* wfl  = (unsigned short*)(ws + 7813632 + 196608);

  prep_wfrag<<<48, 256, 0, stream>>>(W, wfh, wfl);
  colbert_proj_mfma<<<(VOCAB + 31) / 32, 256, 0, stream>>>(emb, wfh, wfl, bias, pebf);
  colbert_score_mfma<<<BATCH, 256, 0, stream>>>(qids, qmask, dids, dmask, pebf, out);
}